// Round 1
// 105.631 us; speedup vs baseline: 1.1392x; 1.1392x over previous
//
#include <hip/hip_runtime.h>
#include <hip/hip_bf16.h>

// GATConv B=8, N=2048, D=64, leaky slope 0.2, multiplicative adj mask.
// exp(e_ij) = 1 + adj_ij*(exp(leaky(s_i+d_j)) - 1)
//   => h'_i = (H_sum + sum_{nbr} w_ij*h_j) / (N + sum_{nbr} w_ij)
// h stored bf16 as h_bf[n][b*64+d]; s_t/dv_t[n][b] fp32.
// proj: x-row operand is wave-uniform -> scalar (s_load) broadcast, W column
//   held in 64 VGPRs (no LDS/bpermute in the fma loop).
// attn: phase 1 compacts nz indices (8 hoisted parallel adj loads);
//   phase 2 inline weights, 2-deep software pipeline (2 edges in flight).

constexpr int Bq = 8;
constexpr int Nq = 2048;
constexpr int MAXL = 256;  // max nnz/row (mean 103, sd ~10)
#define ALPHA 0.2f

// ---- Kernel 1: h = x@W, s/dv logits, fused column-sum ----
__global__ __launch_bounds__(256) void proj_kernel(
    const float* __restrict__ x, const float* __restrict__ W,
    const float* __restrict__ a, __hip_bfloat16* __restrict__ h_bf,
    float* __restrict__ s_t, float* __restrict__ dv_t,
    float* __restrict__ hsumv) {
  __shared__ float red[4][64];
  const int tid = threadIdx.x;
  const int lane = tid & 63;
  const int wv = tid >> 6;

  // W column for this lane's output dim d=lane, held in VGPRs.
  // 64 coalesced 256B loads; L2-hot after the first blocks (W is 16 KB).
  float Wc[64];
#pragma unroll
  for (int k = 0; k < 64; ++k) Wc[k] = W[k * 64 + lane];

  // 4 rows per wave; row index is wave-uniform -> force scalar loads of x.
  const int row0 = __builtin_amdgcn_readfirstlane((int)blockIdx.x * 16 + wv * 4);
  const float* __restrict__ xr = x + (size_t)row0 * 64;

  float acc[4] = {0.f, 0.f, 0.f, 0.f};
#pragma unroll
  for (int k = 0; k < 64; ++k) {
    const float w = Wc[k];
    acc[0] = fmaf(xr[k], w, acc[0]);
    acc[1] = fmaf(xr[64 + k], w, acc[1]);
    acc[2] = fmaf(xr[128 + k], w, acc[2]);
    acc[3] = fmaf(xr[192 + k], w, acc[3]);
  }

  const float aS = a[lane], aD = a[64 + lane];
#pragma unroll
  for (int r = 0; r < 4; ++r) {
    const int row = row0 + r;
    const int b = row >> 11, n = row & 2047;
    h_bf[(size_t)n * 512 + b * 64 + lane] = __float2bfloat16(acc[r]);
    float ps = acc[r] * aS, pd = acc[r] * aD;
#pragma unroll
    for (int off = 32; off; off >>= 1) {
      ps += __shfl_xor(ps, off);
      pd += __shfl_xor(pd, off);
    }
    if (lane == 0) {
      s_t[n * 8 + b] = ps;
      dv_t[n * 8 + b] = pd;
    }
  }
  // fused hsum (fp32): this block's 16 rows belong to one batch
  red[wv][lane] = acc[0] + acc[1] + acc[2] + acc[3];
  __syncthreads();
  if (wv == 0) {
    const int b = blockIdx.x >> 7;
    atomicAdd(&hsumv[b * 64 + lane],
              red[0][lane] + red[1][lane] + red[2][lane] + red[3][lane]);
  }
}

// ---- Kernel 2: one block per row i; compact nz list, inline-weight gather --
__global__ __launch_bounds__(256) void attn_kernel(
    const float* __restrict__ adj, const __hip_bfloat16* __restrict__ h_bf,
    const float* __restrict__ s_t, const float* __restrict__ dv_t,
    const float* __restrict__ hsumv, const float* __restrict__ bias,
    float* __restrict__ out) {
  __shared__ int sJ[MAXL];        // compact nz column indices
  __shared__ float sacc[4][512];  // cross-wave accumulator reduce
  __shared__ float szz[4][8];
  __shared__ int scnt;
  const int i = blockIdx.x;
  const int tid = threadIdx.x;
  const int lane = tid & 63;
  const int wv = tid >> 6;

  if (tid == 0) scnt = 0;
  __syncthreads();

  // Phase 1: hoisted parallel adj loads (read-once: non-temporal), then
  // ballot-compact nz indices into sJ.
  float av[8];
#pragma unroll
  for (int c = 0; c < 8; ++c)
    av[c] = __builtin_nontemporal_load(
        &adj[(size_t)i * Nq + wv * 64 + c * 256 + lane]);
#pragma unroll
  for (int c = 0; c < 8; ++c) {
    const int j = wv * 64 + c * 256 + lane;
    const bool nz = (av[c] != 0.0f) || (j == i);  // fill_diagonal_(1)
    unsigned long long m = __ballot(nz);
    const int cnt = __popcll(m);
    int base = 0;
    if (lane == 0 && cnt) base = atomicAdd(&scnt, cnt);
    base = __shfl(base, 0);
    if (nz) sJ[base + __popcll(m & ((1ULL << lane) - 1))] = j;
  }
  __syncthreads();
  const int L = scnt;

  // Phase 2: lane owns batch g2 = lane>>3, dims (lane&7)*8..+7.
  // Weight computed inline (replicated across the 8 lanes of a group).
  // 2-deep software pipeline: edges e and e+4 in flight simultaneously.
  const int g2 = lane >> 3;
  const int lbase = lane * 8;
  const float sg = s_t[i * 8 + g2];
  float acc[8] = {0.f, 0.f, 0.f, 0.f, 0.f, 0.f, 0.f, 0.f};
  float Zp = 0.f;

#define GAT_ACC(hc, dc)                                          \
  {                                                              \
    float t = sg + (dc);                                         \
    t = (t >= 0.f) ? t : ALPHA * t;                              \
    const float w = __expf(t) - 1.0f;                            \
    Zp += w;                                                     \
    const unsigned u0 = (hc).x, u1 = (hc).y;                     \
    const unsigned u2 = (hc).z, u3 = (hc).w;                     \
    acc[0] = fmaf(w, __uint_as_float(u0 << 16), acc[0]);         \
    acc[1] = fmaf(w, __uint_as_float(u0 & 0xffff0000u), acc[1]); \
    acc[2] = fmaf(w, __uint_as_float(u1 << 16), acc[2]);         \
    acc[3] = fmaf(w, __uint_as_float(u1 & 0xffff0000u), acc[3]); \
    acc[4] = fmaf(w, __uint_as_float(u2 << 16), acc[4]);         \
    acc[5] = fmaf(w, __uint_as_float(u2 & 0xffff0000u), acc[5]); \
    acc[6] = fmaf(w, __uint_as_float(u3 << 16), acc[6]);         \
    acc[7] = fmaf(w, __uint_as_float(u3 & 0xffff0000u), acc[7]); \
  }

  int e = wv;
  uint4 hA, hB;
  float dA = 0.f, dB = 0.f;
  bool hvA = e < L;
  bool hvB = (e + 4) < L;
  if (hvA) {
    const int j = sJ[e];
    dA = dv_t[j * 8 + g2];
    hA = *(const uint4*)(h_bf + (size_t)j * 512 + lbase);
  }
  if (hvB) {
    const int j = sJ[e + 4];
    dB = dv_t[j * 8 + g2];
    hB = *(const uint4*)(h_bf + (size_t)j * 512 + lbase);
  }
  while (hvA) {
    const uint4 hcA = hA;
    const float dcA = dA;
    const bool hvA2 = (e + 8) < L;
    if (hvA2) {
      const int j = sJ[e + 8];
      dA = dv_t[j * 8 + g2];
      hA = *(const uint4*)(h_bf + (size_t)j * 512 + lbase);
    }
    GAT_ACC(hcA, dcA);
    if (!hvB) break;
    const uint4 hcB = hB;
    const float dcB = dB;
    const bool hvB2 = (e + 12) < L;
    if (hvB2) {
      const int j = sJ[e + 12];
      dB = dv_t[j * 8 + g2];
      hB = *(const uint4*)(h_bf + (size_t)j * 512 + lbase);
    }
    GAT_ACC(hcB, dcB);
    e += 8;
    hvA = hvA2;
    hvB = hvB2;
  }
#undef GAT_ACC

  if ((lane & 7) == 0) szz[wv][g2] = Zp;  // w replicated within group

  *(float4*)&sacc[wv][lbase] = make_float4(acc[0], acc[1], acc[2], acc[3]);
  *(float4*)&sacc[wv][lbase + 4] = make_float4(acc[4], acc[5], acc[6], acc[7]);
  __syncthreads();

#pragma unroll
  for (int half = 0; half < 2; ++half) {
    const int ei = tid + half * 256;  // ei = b*64+d
    const float v = sacc[0][ei] + sacc[1][ei] + sacc[2][ei] + sacc[3][ei];
    const int b = ei >> 6, d = ei & 63;
    const float Z = (float)Nq + szz[0][b] + szz[1][b] + szz[2][b] + szz[3][b];
    out[(size_t)(b * Nq + i) * 64 + d] =
        (hsumv[ei] + v) * __builtin_amdgcn_rcpf(Z) + bias[d];
  }
}

extern "C" void kernel_launch(void* const* d_in, const int* in_sizes, int n_in,
                              void* d_out, int out_size, void* d_ws,
                              size_t ws_size, hipStream_t stream) {
  const float* x = (const float*)d_in[0];     // [B,N,64]
  const float* adj = (const float*)d_in[1];   // [N,N]
  const float* W = (const float*)d_in[2];     // [64,64]
  const float* a = (const float*)d_in[3];     // [128,1]
  const float* bias = (const float*)d_in[4];  // [64]
  float* out = (float*)d_out;                 // [B,N,64] fp32

  float* s_t = (float*)d_ws;              // N*B
  float* dv_t = s_t + (size_t)Nq * Bq;    // N*B
  float* hsumv = dv_t + (size_t)Nq * Bq;  // B*64
  __hip_bfloat16* h_bf = (__hip_bfloat16*)(hsumv + 512);  // N*512 bf16, 2MB

  hipMemsetAsync(hsumv, 0, 512 * sizeof(float), stream);
  proj_kernel<<<1024, 256, 0, stream>>>(x, W, a, h_bf, s_t, dv_t, hsumv);
  attn_kernel<<<Nq, 256, 0, stream>>>(adj, h_bf, s_t, dv_t, hsumv, bias, out);
}